// Round 1
// baseline (166.805 us; speedup 1.0000x reference)
//
#include <hip/hip_runtime.h>

typedef unsigned int uint;
typedef unsigned short ushort_t;

typedef __attribute__((ext_vector_type(8))) short bf16x8;
typedef __attribute__((ext_vector_type(4))) float f32x4;

#define E_CNT 496

__device__ __forceinline__ ushort_t f32_to_bf16_rn(float x) {
    uint u = __float_as_uint(x);
    u = (u + 0x7fffu + ((u >> 16) & 1u)) >> 16;
    return (ushort_t)u;
}

// ---------------- edge decode (int64 vs int32 auto-detect) ----------------
__global__ void decode_edges_kernel(const int* __restrict__ sf, const int* __restrict__ st,
                                    int* __restrict__ ef, int* __restrict__ et) {
    int j = threadIdx.x;
    bool f64 = true, t64 = true;
    #pragma unroll
    for (int i = 0; i < 16; ++i) {
        if (sf[2 * i + 1] != 0) f64 = false;
        if (st[2 * i + 1] != 0) t64 = false;
    }
    if (j < E_CNT) {
        ef[j] = f64 ? sf[2 * j] : sf[j];
        et[j] = t64 ? st[2 * j] : st[j];
    }
}

// ---------------- X staging: X1 = W1a*h + b1/2, X2 = W1b*h + b1/2 (bf16) ----------------
__global__ __launch_bounds__(256) void x_kernel(const float* __restrict__ hidden,
                                                const float* __restrict__ W1,
                                                const float* __restrict__ b1,
                                                ushort_t* __restrict__ X1,
                                                ushort_t* __restrict__ X2) {
    __shared__ float hidT[128 * 20];  // [d][r], stride 20 -> aligned float4 broadcasts
    const int tid = threadIdx.x;
    const int row0 = blockIdx.x * 16;
    #pragma unroll
    for (int j = 0; j < 8; ++j) {
        int lin = tid + j * 256;
        int r = lin >> 7, d = lin & 127;
        hidT[d * 20 + r] = hidden[row0 * 128 + lin];
    }
    __syncthreads();
    float acc1[16], acc2[16];
    #pragma unroll
    for (int r = 0; r < 16; ++r) { acc1[r] = 0.f; acc2[r] = 0.f; }
    const int h = tid;
    const float* w1a = W1 + h * 256;
    const float* w1b = w1a + 128;
    for (int d = 0; d < 128; ++d) {
        float wa = w1a[d], wb = w1b[d];
        float hv[16];
        *(float4*)&hv[0]  = *(const float4*)&hidT[d * 20 + 0];
        *(float4*)&hv[4]  = *(const float4*)&hidT[d * 20 + 4];
        *(float4*)&hv[8]  = *(const float4*)&hidT[d * 20 + 8];
        *(float4*)&hv[12] = *(const float4*)&hidT[d * 20 + 12];
        #pragma unroll
        for (int r = 0; r < 16; ++r) {
            acc1[r] = fmaf(wa, hv[r], acc1[r]);
            acc2[r] = fmaf(wb, hv[r], acc2[r]);
        }
    }
    float bh = 0.5f * b1[h];
    #pragma unroll
    for (int r = 0; r < 16; ++r) {
        X1[(row0 + r) * 256 + h] = f32_to_bf16_rn(acc1[r] + bh);
        X2[(row0 + r) * 256 + h] = f32_to_bf16_rn(acc2[r] + bh);
    }
}

// ---------------- fused GEMM2 (MFMA) + payoff ----------------
// block = 512 threads = 8 waves; each wave: 16 rows = {s0,s1} x 8 pairs; block = 64 pairs.
__global__ __launch_bounds__(512) void gemm_payoff_kernel(
    const ushort_t* __restrict__ X1, const ushort_t* __restrict__ X2,
    const int* __restrict__ ef, const int* __restrict__ et,
    const float* __restrict__ W2, const float* __restrict__ b2,
    float* __restrict__ out) {

    __shared__ __align__(16) unsigned char smem[50688];
    ushort_t* w2s = (ushort_t*)smem;  // phase 1: W2 bf16 [96][264]
    float* pf = (float*)smem;         // phase 2: per-wave 1536 floats (L:768, R:768)

    const int tid = threadIdx.x;

    // stage W2 -> LDS (bf16, row stride 264 halves => conflict-free B reads)
    #pragma unroll
    for (int j = 0; j < 12; ++j) {
        int idx4 = tid + j * 512;  // 0..6143 float4s
        int n = idx4 >> 6;
        int k = (idx4 & 63) << 2;
        float4 v = *(const float4*)&W2[n * 256 + k];
        ushort_t* dst = &w2s[n * 264 + k];
        dst[0] = f32_to_bf16_rn(v.x);
        dst[1] = f32_to_bf16_rn(v.y);
        dst[2] = f32_to_bf16_rn(v.z);
        dst[3] = f32_to_bf16_rn(v.w);
    }

    const int ln = tid & 63;
    const int waveId = tid >> 6;
    const int quad = ln >> 4;
    const int l16 = ln & 15;
    const int pl = l16 & 7;
    const int s = l16 >> 3;

    const int pairBase = blockIdx.x * 64 + waveId * 8;
    const int pair = pairBase + pl;
    const int b = pair / E_CNT;
    const int e = pair - b * E_CNT;
    const int f = ef[e];
    const int t = et[e];
    const int n1 = s ? t : f;
    const int n2 = s ? f : t;
    const ushort_t* px1 = X1 + ((b * 32 + n1) * 256 + quad * 8);
    const ushort_t* px2 = X2 + ((b * 32 + n2) * 256 + quad * 8);

    float b2v[6];
    #pragma unroll
    for (int tt = 0; tt < 6; ++tt) b2v[tt] = b2[tt * 16 + l16];

    f32x4 acc[6];
    #pragma unroll
    for (int tt = 0; tt < 6; ++tt) acc[tt] = (f32x4){0.f, 0.f, 0.f, 0.f};

    __syncthreads();

    // K-loop: 8 steps of 32; A-frag built in-register (gather X1/X2, add, relu, pack)
    #pragma unroll
    for (int kk = 0; kk < 8; ++kk) {
        uint4 a1 = *(const uint4*)(px1 + kk * 32);
        uint4 a2 = *(const uint4*)(px2 + kk * 32);
        uint ua[4] = {a1.x, a1.y, a1.z, a1.w};
        uint ub[4] = {a2.x, a2.y, a2.z, a2.w};
        union { uint u[4]; bf16x8 v; } af;
        #pragma unroll
        for (int w = 0; w < 4; ++w) {
            float lo = __uint_as_float(ua[w] << 16) + __uint_as_float(ub[w] << 16);
            float hi = __uint_as_float(ua[w] & 0xffff0000u) + __uint_as_float(ub[w] & 0xffff0000u);
            lo = fmaxf(lo, 0.f);
            hi = fmaxf(hi, 0.f);
            af.u[w] = (__float_as_uint(lo) >> 16) | (__float_as_uint(hi) & 0xffff0000u);
        }
        #pragma unroll
        for (int tt = 0; tt < 6; ++tt) {
            const int nrow = tt * 16 + l16;
            bf16x8 bf = *(const bf16x8*)&w2s[nrow * 264 + kk * 32 + quad * 8];
            acc[tt] = __builtin_amdgcn_mfma_f32_16x16x32_bf16(af.v, bf, acc[tt], 0, 0, 0);
        }
    }

    __syncthreads();  // all waves done with w2s; LDS repurposed below

    // dump p (+b2) into payoff layout:
    //   n = rr*24 + c01*12 + a;  row = quad*4+r -> (s_, pl_)
    //   L[pl_][a][k8] gets s0/c0 (U0, k8=rr) and s1/c1 (V1, k8=4+rr)
    //   R[pl_][a][k8] gets s0/c1 (V0)        and s1/c0 (U1)
    float* wbase = pf + waveId * 1536;
    #pragma unroll
    for (int tt = 0; tt < 6; ++tt) {
        const int n = tt * 16 + l16;
        const int rr = n / 24;
        const int rem = n - rr * 24;
        const int c01 = (rem >= 12) ? 1 : 0;
        const int a = rem - c01 * 12;
        #pragma unroll
        for (int r = 0; r < 4; ++r) {
            const int row = quad * 4 + r;
            const int s_ = row >> 3;
            const int pl_ = row & 7;
            const int k8 = (s_ ? 4 : 0) + rr;
            const int toL = (c01 == s_) ? 1 : 0;
            float val = acc[tt][r] + b2v[tt];
            wbase[(toL ? 0 : 768) + pl_ * 96 + a * 8 + k8] = val;
        }
    }

    __syncthreads();

    // payoff: out[i][j] = 0.5 * sum_{k8} L[i][k8] * R[j][k8]
    #pragma unroll
    for (int it = 0; it < 2; ++it) {
        int task = it * 64 + ln;
        if (task < 96) {
            int pp = task / 12;
            int i = task - pp * 12;
            const float* Lp = wbase + pp * 96 + i * 8;
            float4 l0 = *(const float4*)&Lp[0];
            float4 l1 = *(const float4*)&Lp[4];
            float od[12];
            #pragma unroll
            for (int jj = 0; jj < 12; ++jj) {
                const float* Rp = wbase + 768 + pp * 96 + jj * 8;
                float4 r0 = *(const float4*)&Rp[0];
                float4 r1 = *(const float4*)&Rp[4];
                float d = l0.x * r0.x + l0.y * r0.y + l0.z * r0.z + l0.w * r0.w
                        + l1.x * r1.x + l1.y * r1.y + l1.z * r1.z + l1.w * r1.w;
                od[jj] = 0.5f * d;
            }
            int outBase = (pairBase + pp) * 144 + i * 12;
            *(float4*)&out[outBase + 0] = make_float4(od[0], od[1], od[2], od[3]);
            *(float4*)&out[outBase + 4] = make_float4(od[4], od[5], od[6], od[7]);
            *(float4*)&out[outBase + 8] = make_float4(od[8], od[9], od[10], od[11]);
        }
    }
}

extern "C" void kernel_launch(void* const* d_in, const int* in_sizes, int n_in,
                              void* d_out, int out_size, void* d_ws, size_t ws_size,
                              hipStream_t stream) {
    const float* hidden = (const float*)d_in[0];
    const float* W1 = (const float*)d_in[1];
    const float* b1 = (const float*)d_in[2];
    const float* W2 = (const float*)d_in[3];
    const float* b2 = (const float*)d_in[4];
    const int* e_f = (const int*)d_in[5];
    const int* e_t = (const int*)d_in[6];
    float* out = (float*)d_out;

    char* ws = (char*)d_ws;
    int* ef = (int*)ws;
    int* et = (int*)(ws + 2048);
    ushort_t* X1 = (ushort_t*)(ws + 8192);
    ushort_t* X2 = (ushort_t*)(ws + 8192 + 4 * 1024 * 1024);

    decode_edges_kernel<<<1, 512, 0, stream>>>(e_f, e_t, ef, et);
    x_kernel<<<512, 256, 0, stream>>>(hidden, W1, b1, X1, X2);
    gemm_payoff_kernel<<<1984, 512, 0, stream>>>(X1, X2, ef, et, W2, b2, out);
}

// Round 2
// 158.815 us; speedup vs baseline: 1.0503x; 1.0503x over previous
//
#include <hip/hip_runtime.h>

typedef unsigned int uint;
typedef unsigned short ushort_t;

typedef __attribute__((ext_vector_type(8))) short bf16x8;
typedef __attribute__((ext_vector_type(4))) float f32x4;

#define E_CNT 496

__device__ __forceinline__ ushort_t f32_to_bf16_rn(float x) {
    uint u = __float_as_uint(x);
    u = (u + 0x7fffu + ((u >> 16) & 1u)) >> 16;
    return (ushort_t)u;
}

// ---------------- prep: edge decode (block 0) + W1 transpose (blocks 1..16) ----------------
__global__ __launch_bounds__(256) void prep_kernel(const int* __restrict__ sf, const int* __restrict__ st,
                                                   const float* __restrict__ W1,
                                                   int* __restrict__ ef, int* __restrict__ et,
                                                   float* __restrict__ W1T) {
    const int tid = threadIdx.x;
    if (blockIdx.x == 0) {
        // edge decode with int64/int32 auto-detect
        bool f64 = true, t64 = true;
        #pragma unroll
        for (int i = 0; i < 16; ++i) {
            if (sf[2 * i + 1] != 0) f64 = false;
            if (st[2 * i + 1] != 0) t64 = false;
        }
        for (int j = tid; j < E_CNT; j += 256) {
            ef[j] = f64 ? sf[2 * j] : sf[j];
            et[j] = t64 ? st[2 * j] : st[j];
        }
        return;
    }
    // 64x64 tile transpose of W1 (256x256 f32) -> W1T[d][h]
    __shared__ float tile[64][65];
    const int t = blockIdx.x - 1;
    const int tr = t >> 2;        // row-tile of W1 (h)
    const int tc = t & 3;         // col-tile of W1 (d)
    const int tx = tid & 63;
    const int ty4 = tid >> 6;     // 0..3
    #pragma unroll
    for (int rr = 0; rr < 16; ++rr) {
        int row = rr * 4 + ty4;
        tile[row][tx] = W1[(tr * 64 + row) * 256 + tc * 64 + tx];
    }
    __syncthreads();
    #pragma unroll
    for (int rr = 0; rr < 16; ++rr) {
        int row = rr * 4 + ty4;
        W1T[(tc * 64 + row) * 256 + tr * 64 + tx] = tile[tx][row];
    }
}

// ---------------- X staging: X1 = W1a*h + b1/2, X2 = W1b*h + b1/2 (bf16) ----------------
// lane = h, W1T reads coalesced; hidden reads wave-uniform (scalar path). No LDS.
__global__ __launch_bounds__(256) void x_kernel(const float* __restrict__ hidden,
                                                const float* __restrict__ W1T,
                                                const float* __restrict__ b1,
                                                ushort_t* __restrict__ X1,
                                                ushort_t* __restrict__ X2) {
    const int h = threadIdx.x;
    const int row0 = blockIdx.x * 16;
    const float* __restrict__ hb = hidden + row0 * 128;
    const float* __restrict__ w1ta = W1T + h;
    const float* __restrict__ w1tb = W1T + 128 * 256 + h;

    float acc1[16], acc2[16];
    #pragma unroll
    for (int r = 0; r < 16; ++r) { acc1[r] = 0.f; acc2[r] = 0.f; }

    #pragma unroll 4
    for (int d = 0; d < 128; ++d) {
        float wa = w1ta[d * 256];
        float wb = w1tb[d * 256];
        #pragma unroll
        for (int r = 0; r < 16; ++r) {
            float hv = hb[r * 128 + d];   // wave-uniform -> s_load
            acc1[r] = fmaf(wa, hv, acc1[r]);
            acc2[r] = fmaf(wb, hv, acc2[r]);
        }
    }
    float bh = 0.5f * b1[h];
    #pragma unroll
    for (int r = 0; r < 16; ++r) {
        X1[(row0 + r) * 256 + h] = f32_to_bf16_rn(acc1[r] + bh);
        X2[(row0 + r) * 256 + h] = f32_to_bf16_rn(acc2[r] + bh);
    }
}

// ---------------- fused GEMM2 (MFMA) + payoff ----------------
// block = 512 threads = 8 waves; each wave: 16 rows = {s0,s1} x 8 pairs; block = 64 pairs.
#define PAIR_STRIDE 100   // floats; 100 % 32 == 4 -> 8 pp values tile all bank quads
#define R_OFF 800         // 8 * PAIR_STRIDE
#define WAVE_PF 1600      // floats per wave (L + R)

__global__ __launch_bounds__(512) void gemm_payoff_kernel(
    const ushort_t* __restrict__ X1, const ushort_t* __restrict__ X2,
    const int* __restrict__ ef, const int* __restrict__ et,
    const float* __restrict__ W2, const float* __restrict__ b2,
    float* __restrict__ out) {

    __shared__ __align__(16) unsigned char smem[51200];
    ushort_t* w2s = (ushort_t*)smem;  // phase 1: W2 bf16 [96][264] = 50688 B
    float* pf = (float*)smem;         // phase 2: per-wave 1600 floats (L:800, R:800)

    const int tid = threadIdx.x;

    // stage W2 -> LDS (bf16, row stride 264 halves)
    #pragma unroll
    for (int j = 0; j < 12; ++j) {
        int idx4 = tid + j * 512;  // 0..6143 float4s
        int n = idx4 >> 6;
        int k = (idx4 & 63) << 2;
        float4 v = *(const float4*)&W2[n * 256 + k];
        ushort_t* dst = &w2s[n * 264 + k];
        dst[0] = f32_to_bf16_rn(v.x);
        dst[1] = f32_to_bf16_rn(v.y);
        dst[2] = f32_to_bf16_rn(v.z);
        dst[3] = f32_to_bf16_rn(v.w);
    }

    const int ln = tid & 63;
    const int waveId = tid >> 6;
    const int quad = ln >> 4;
    const int l16 = ln & 15;
    const int pl = l16 & 7;
    const int s = l16 >> 3;

    const int pairBase = blockIdx.x * 64 + waveId * 8;
    const int pair = pairBase + pl;
    const int b = pair / E_CNT;
    const int e = pair - b * E_CNT;
    const int f = ef[e];
    const int t = et[e];
    const int n1 = s ? t : f;
    const int n2 = s ? f : t;
    const ushort_t* px1 = X1 + ((b * 32 + n1) * 256 + quad * 8);
    const ushort_t* px2 = X2 + ((b * 32 + n2) * 256 + quad * 8);

    float b2v[6];
    #pragma unroll
    for (int tt = 0; tt < 6; ++tt) b2v[tt] = b2[tt * 16 + l16];

    f32x4 acc[6];
    #pragma unroll
    for (int tt = 0; tt < 6; ++tt) acc[tt] = (f32x4){0.f, 0.f, 0.f, 0.f};

    __syncthreads();

    // K-loop: 8 steps of 32; A-frag built in-register (gather X1/X2, add, relu, pack)
    #pragma unroll
    for (int kk = 0; kk < 8; ++kk) {
        uint4 a1 = *(const uint4*)(px1 + kk * 32);
        uint4 a2 = *(const uint4*)(px2 + kk * 32);
        uint ua[4] = {a1.x, a1.y, a1.z, a1.w};
        uint ub[4] = {a2.x, a2.y, a2.z, a2.w};
        union { uint u[4]; bf16x8 v; } af;
        #pragma unroll
        for (int w = 0; w < 4; ++w) {
            float lo = __uint_as_float(ua[w] << 16) + __uint_as_float(ub[w] << 16);
            float hi = __uint_as_float(ua[w] & 0xffff0000u) + __uint_as_float(ub[w] & 0xffff0000u);
            lo = fmaxf(lo, 0.f);
            hi = fmaxf(hi, 0.f);
            af.u[w] = (__float_as_uint(lo) >> 16) | (__float_as_uint(hi) & 0xffff0000u);
        }
        #pragma unroll
        for (int tt = 0; tt < 6; ++tt) {
            const int nrow = tt * 16 + l16;
            bf16x8 bf = *(const bf16x8*)&w2s[nrow * 264 + kk * 32 + quad * 8];
            acc[tt] = __builtin_amdgcn_mfma_f32_16x16x32_bf16(af.v, bf, acc[tt], 0, 0, 0);
        }
    }

    __syncthreads();  // all waves done with w2s; LDS repurposed below

    // dump p (+b2) into payoff layout:
    //   n = rr*24 + c01*12 + a;  row = quad*4+r -> (s_, pl_)
    //   L[pl_][a][k8] gets s0/c0 (U0, k8=rr) and s1/c1 (V1, k8=4+rr)
    //   R[pl_][a][k8] gets s0/c1 (V0)        and s1/c0 (U1)
    float* wbase = pf + waveId * WAVE_PF;
    #pragma unroll
    for (int tt = 0; tt < 6; ++tt) {
        const int n = tt * 16 + l16;
        const int rr = n / 24;
        const int rem = n - rr * 24;
        const int c01 = (rem >= 12) ? 1 : 0;
        const int a = rem - c01 * 12;
        #pragma unroll
        for (int r = 0; r < 4; ++r) {
            const int row = quad * 4 + r;
            const int s_ = row >> 3;
            const int pl_ = row & 7;
            const int k8 = (s_ ? 4 : 0) + rr;
            const int toL = (c01 == s_) ? 1 : 0;
            float val = acc[tt][r] + b2v[tt];
            wbase[(toL ? 0 : R_OFF) + pl_ * PAIR_STRIDE + a * 8 + k8] = val;
        }
    }

    __syncthreads();

    // payoff: out[i][j] = 0.5 * sum_{k8} L[i][k8] * R[j][k8]
    #pragma unroll
    for (int it = 0; it < 2; ++it) {
        int task = it * 64 + ln;
        if (task < 96) {
            int pp = task / 12;
            int i = task - pp * 12;
            const float* Lp = wbase + pp * PAIR_STRIDE + i * 8;
            float4 l0 = *(const float4*)&Lp[0];
            float4 l1 = *(const float4*)&Lp[4];
            float od[12];
            #pragma unroll
            for (int jj = 0; jj < 12; ++jj) {
                const float* Rp = wbase + R_OFF + pp * PAIR_STRIDE + jj * 8;
                float4 r0 = *(const float4*)&Rp[0];
                float4 r1 = *(const float4*)&Rp[4];
                float d = l0.x * r0.x + l0.y * r0.y + l0.z * r0.z + l0.w * r0.w
                        + l1.x * r1.x + l1.y * r1.y + l1.z * r1.z + l1.w * r1.w;
                od[jj] = 0.5f * d;
            }
            int outBase = (pairBase + pp) * 144 + i * 12;
            *(float4*)&out[outBase + 0] = make_float4(od[0], od[1], od[2], od[3]);
            *(float4*)&out[outBase + 4] = make_float4(od[4], od[5], od[6], od[7]);
            *(float4*)&out[outBase + 8] = make_float4(od[8], od[9], od[10], od[11]);
        }
    }
}

extern "C" void kernel_launch(void* const* d_in, const int* in_sizes, int n_in,
                              void* d_out, int out_size, void* d_ws, size_t ws_size,
                              hipStream_t stream) {
    const float* hidden = (const float*)d_in[0];
    const float* W1 = (const float*)d_in[1];
    const float* b1 = (const float*)d_in[2];
    const float* W2 = (const float*)d_in[3];
    const float* b2 = (const float*)d_in[4];
    const int* e_f = (const int*)d_in[5];
    const int* e_t = (const int*)d_in[6];
    float* out = (float*)d_out;

    char* ws = (char*)d_ws;
    int* ef = (int*)ws;                         // 2 KB
    int* et = (int*)(ws + 2048);                // 2 KB
    float* W1T = (float*)(ws + 8192);           // 256 KB
    ushort_t* X1 = (ushort_t*)(ws + 270336);    // 4 MB
    ushort_t* X2 = (ushort_t*)(ws + 270336 + 4 * 1024 * 1024);

    prep_kernel<<<17, 256, 0, stream>>>(e_f, e_t, W1, ef, et, W1T);
    x_kernel<<<512, 256, 0, stream>>>(hidden, W1T, b1, X1, X2);
    gemm_payoff_kernel<<<1984, 512, 0, stream>>>(X1, X2, ef, et, W2, b2, out);
}

// Round 3
// 146.862 us; speedup vs baseline: 1.1358x; 1.0814x over previous
//
#include <hip/hip_runtime.h>

typedef unsigned int uint;
typedef unsigned short ushort_t;

typedef __attribute__((ext_vector_type(8))) short bf16x8;
typedef __attribute__((ext_vector_type(4))) float f32x4;

#define E_CNT 496

__device__ __forceinline__ ushort_t f32_to_bf16_rn(float x) {
    uint u = __float_as_uint(x);
    u = (u + 0x7fffu + ((u >> 16) & 1u)) >> 16;
    return (ushort_t)u;
}
__device__ __forceinline__ uint pack2_bf16(float lo, float hi) {
    return (uint)f32_to_bf16_rn(lo) | ((uint)f32_to_bf16_rn(hi) << 16);
}

// ---------------- prep: W1 -> swizzled bf16 image, W2 -> bf16 LDS image, edge decode ----
// blocks 0..31: W1 image [2 halves][256 h][128 d] bf16, 16B chunk c stored at c^(h&7)
// blocks 32..43: W2 image [96][264] bf16 (k-contiguous, padded rows)
// block 44: edge decode
__global__ __launch_bounds__(256) void prep_kernel(
    const int* __restrict__ sf, const int* __restrict__ st,
    const float* __restrict__ W1, const float* __restrict__ W2,
    int* __restrict__ ef, int* __restrict__ et,
    ushort_t* __restrict__ w1img, ushort_t* __restrict__ w2img) {
    const int tid = threadIdx.x;
    const int blk = blockIdx.x;
    if (blk < 32) {
        int gid = blk * 256 + tid;     // [0, 8192)
        int half = gid >> 12;
        int rem = gid & 4095;
        int h = rem >> 4;
        int c = rem & 15;
        const float* src = W1 + h * 256 + half * 128 + c * 8;
        float4 v0 = *(const float4*)src;
        float4 v1 = *(const float4*)(src + 4);
        uint4 o;
        o.x = pack2_bf16(v0.x, v0.y);
        o.y = pack2_bf16(v0.z, v0.w);
        o.z = pack2_bf16(v1.x, v1.y);
        o.w = pack2_bf16(v1.z, v1.w);
        int dst = half * 32768 + h * 128 + ((c ^ (h & 7)) << 3);
        *(uint4*)(w1img + dst) = o;
    } else if (blk < 44) {
        int gid = (blk - 32) * 256 + tid;  // [0, 3072)
        int n = gid >> 5;
        int c = gid & 31;
        const float* src = W2 + n * 256 + c * 8;
        float4 v0 = *(const float4*)src;
        float4 v1 = *(const float4*)(src + 4);
        uint4 o;
        o.x = pack2_bf16(v0.x, v0.y);
        o.y = pack2_bf16(v0.z, v0.w);
        o.z = pack2_bf16(v1.x, v1.y);
        o.w = pack2_bf16(v1.z, v1.w);
        *(uint4*)(w2img + n * 264 + c * 8) = o;
    } else {
        bool f64 = true, t64 = true;
        #pragma unroll
        for (int i = 0; i < 16; ++i) {
            if (sf[2 * i + 1] != 0) f64 = false;
            if (st[2 * i + 1] != 0) t64 = false;
        }
        for (int j = tid; j < E_CNT; j += 256) {
            ef[j] = f64 ? sf[2 * j] : sf[j];
            et[j] = t64 ? st[2 * j] : st[j];
        }
    }
}

// ---------------- X staging via MFMA: X{1,2}[row][h] = W1half . hidden[row] + b1/2 ------
// grid = 128 M-tiles x 2 halves; block = 256 thr = 4 waves; wave owns 16 rows.
__global__ __launch_bounds__(256) void x_kernel(
    const float* __restrict__ hidden, const ushort_t* __restrict__ w1img,
    const float* __restrict__ b1, ushort_t* __restrict__ Xout) {
    __shared__ __align__(16) ushort_t w1s[256 * 128];  // 64 KB swizzled image

    const int tid = threadIdx.x;
    const int half = blockIdx.x & 1;
    const int mblk = blockIdx.x >> 1;

    // stage image (linear 64 KB copy)
    {
        const uint4* gsrc = (const uint4*)(w1img + half * 32768);
        uint4* ldst = (uint4*)w1s;
        #pragma unroll
        for (int j = 0; j < 16; ++j) ldst[tid + j * 256] = gsrc[tid + j * 256];
    }

    const int ln = tid & 63;
    const int waveId = tid >> 6;
    const int quad = ln >> 4;
    const int l16 = ln & 15;
    const int row0 = mblk * 64 + waveId * 16;

    // A-frags from global f32 (held in regs, reused over all 16 n-tiles)
    union { uint u[4]; bf16x8 v; } af[4];
    const float* arow = hidden + (row0 + l16) * 128 + quad * 8;
    #pragma unroll
    for (int kk = 0; kk < 4; ++kk) {
        float4 v0 = *(const float4*)(arow + kk * 32);
        float4 v1 = *(const float4*)(arow + kk * 32 + 4);
        af[kk].u[0] = pack2_bf16(v0.x, v0.y);
        af[kk].u[1] = pack2_bf16(v0.z, v0.w);
        af[kk].u[2] = pack2_bf16(v1.x, v1.y);
        af[kk].u[3] = pack2_bf16(v1.z, v1.w);
    }
    __syncthreads();

    ushort_t* xbase = Xout + half * (8192 * 256);
    #pragma unroll
    for (int nt = 0; nt < 16; ++nt) {
        const int h = nt * 16 + l16;
        f32x4 acc = (f32x4){0.f, 0.f, 0.f, 0.f};
        #pragma unroll
        for (int kk = 0; kk < 4; ++kk) {
            const int c_log = kk * 4 + quad;
            bf16x8 bf = *(const bf16x8*)&w1s[h * 128 + ((c_log ^ (h & 7)) << 3)];
            acc = __builtin_amdgcn_mfma_f32_16x16x32_bf16(af[kk].v, bf, acc, 0, 0, 0);
        }
        const float bh = 0.5f * b1[h];
        #pragma unroll
        for (int r = 0; r < 4; ++r) {
            const int row = row0 + quad * 4 + r;
            xbase[row * 256 + h] = f32_to_bf16_rn(acc[r] + bh);
        }
    }
}

// ---------------- fused GEMM2 (MFMA) + payoff ----------------
// block = 512 thr = 8 waves; 128 pairs/block (16/wave as 2 m-tiles of {s0,s1}x8 pairs).
#define PAIR_STRIDE 100
#define R_OFF 800
#define WAVE_PF 1600

__global__ __launch_bounds__(512, 4) void gemm_payoff_kernel(
    const ushort_t* __restrict__ X1, const ushort_t* __restrict__ X2,
    const int* __restrict__ ef, const int* __restrict__ et,
    const ushort_t* __restrict__ w2img, const float* __restrict__ b2,
    float* __restrict__ out) {

    __shared__ __align__(16) unsigned char smem[51200];
    ushort_t* w2s = (ushort_t*)smem;  // phase 1: W2 bf16 [96][264] = 50688 B
    float* pf = (float*)smem;         // phase 2: per-wave 1600 floats

    const int tid = threadIdx.x;

    // stage pre-converted W2 image: 3168 x 16B linear copy
    {
        const uint4* src = (const uint4*)w2img;
        uint4* dst = (uint4*)smem;
        #pragma unroll
        for (int j = 0; j < 7; ++j) {
            int idx = tid + j * 512;
            if (idx < 3168) dst[idx] = src[idx];
        }
    }

    const int ln = tid & 63;
    const int waveId = tid >> 6;
    const int quad = ln >> 4;
    const int l16 = ln & 15;
    const int pl = l16 & 7;
    const int s = l16 >> 3;

    const int pairBase = blockIdx.x * 128 + waveId * 16;
    const ushort_t* px1[2];
    const ushort_t* px2[2];
    #pragma unroll
    for (int mt = 0; mt < 2; ++mt) {
        int pair = pairBase + mt * 8 + pl;
        int b = pair / E_CNT;
        int e = pair - b * E_CNT;
        int f = ef[e];
        int t = et[e];
        int n1 = s ? t : f;
        int n2 = s ? f : t;
        px1[mt] = X1 + ((b * 32 + n1) * 256 + quad * 8);
        px2[mt] = X2 + ((b * 32 + n2) * 256 + quad * 8);
    }

    float b2v[6];
    #pragma unroll
    for (int tt = 0; tt < 6; ++tt) b2v[tt] = b2[tt * 16 + l16];

    f32x4 acc[2][6];
    #pragma unroll
    for (int mt = 0; mt < 2; ++mt)
        #pragma unroll
        for (int tt = 0; tt < 6; ++tt) acc[mt][tt] = (f32x4){0.f, 0.f, 0.f, 0.f};

    __syncthreads();

    #pragma unroll
    for (int kk = 0; kk < 8; ++kk) {
        union { uint u[4]; bf16x8 v; } af[2];
        #pragma unroll
        for (int mt = 0; mt < 2; ++mt) {
            uint4 a1 = *(const uint4*)(px1[mt] + kk * 32);
            uint4 a2 = *(const uint4*)(px2[mt] + kk * 32);
            uint ua[4] = {a1.x, a1.y, a1.z, a1.w};
            uint ub[4] = {a2.x, a2.y, a2.z, a2.w};
            #pragma unroll
            for (int w = 0; w < 4; ++w) {
                float lo = __uint_as_float(ua[w] << 16) + __uint_as_float(ub[w] << 16);
                float hi = __uint_as_float(ua[w] & 0xffff0000u) + __uint_as_float(ub[w] & 0xffff0000u);
                lo = fmaxf(lo, 0.f);
                hi = fmaxf(hi, 0.f);
                af[mt].u[w] = (__float_as_uint(lo) >> 16) | (__float_as_uint(hi) & 0xffff0000u);
            }
        }
        #pragma unroll
        for (int tt = 0; tt < 6; ++tt) {
            bf16x8 bf = *(const bf16x8*)&w2s[(tt * 16 + l16) * 264 + kk * 32 + quad * 8];
            acc[0][tt] = __builtin_amdgcn_mfma_f32_16x16x32_bf16(af[0].v, bf, acc[0][tt], 0, 0, 0);
            acc[1][tt] = __builtin_amdgcn_mfma_f32_16x16x32_bf16(af[1].v, bf, acc[1][tt], 0, 0, 0);
        }
    }

    float* wbase = pf + waveId * WAVE_PF;
    #pragma unroll
    for (int mt = 0; mt < 2; ++mt) {
        __syncthreads();  // mt0: all K-loop reads of w2s done; mt1: payoff(mt0) reads done

        // dump p (+b2) into payoff layout
        #pragma unroll
        for (int tt = 0; tt < 6; ++tt) {
            const int n = tt * 16 + l16;
            const int rr = n / 24;
            const int rem = n - rr * 24;
            const int c01 = (rem >= 12) ? 1 : 0;
            const int a = rem - c01 * 12;
            #pragma unroll
            for (int r = 0; r < 4; ++r) {
                const int row = quad * 4 + r;
                const int s_ = row >> 3;
                const int pl_ = row & 7;
                const int k8 = (s_ ? 4 : 0) + rr;
                const int toL = (c01 == s_) ? 1 : 0;
                wbase[(toL ? 0 : R_OFF) + pl_ * PAIR_STRIDE + a * 8 + k8] = acc[mt][tt][r] + b2v[tt];
            }
        }
        __syncthreads();

        // payoff: out[i][j] = 0.5 * sum_k8 L[i][k8]*R[j][k8]
        #pragma unroll
        for (int it = 0; it < 2; ++it) {
            int task = it * 64 + ln;
            if (task < 96) {
                int pp = task / 12;
                int i = task - pp * 12;
                const float* Lp = wbase + pp * PAIR_STRIDE + i * 8;
                float4 l0 = *(const float4*)&Lp[0];
                float4 l1 = *(const float4*)&Lp[4];
                float od[12];
                #pragma unroll
                for (int jj = 0; jj < 12; ++jj) {
                    const float* Rp = wbase + R_OFF + pp * PAIR_STRIDE + jj * 8;
                    float4 r0 = *(const float4*)&Rp[0];
                    float4 r1 = *(const float4*)&Rp[4];
                    float d = l0.x * r0.x + l0.y * r0.y + l0.z * r0.z + l0.w * r0.w
                            + l1.x * r1.x + l1.y * r1.y + l1.z * r1.z + l1.w * r1.w;
                    od[jj] = 0.5f * d;
                }
                int outBase = (pairBase + mt * 8 + pp) * 144 + i * 12;
                *(float4*)&out[outBase + 0] = make_float4(od[0], od[1], od[2], od[3]);
                *(float4*)&out[outBase + 4] = make_float4(od[4], od[5], od[6], od[7]);
                *(float4*)&out[outBase + 8] = make_float4(od[8], od[9], od[10], od[11]);
            }
        }
    }
}

extern "C" void kernel_launch(void* const* d_in, const int* in_sizes, int n_in,
                              void* d_out, int out_size, void* d_ws, size_t ws_size,
                              hipStream_t stream) {
    const float* hidden = (const float*)d_in[0];
    const float* W1 = (const float*)d_in[1];
    const float* b1 = (const float*)d_in[2];
    const float* W2 = (const float*)d_in[3];
    const float* b2 = (const float*)d_in[4];
    const int* e_f = (const int*)d_in[5];
    const int* e_t = (const int*)d_in[6];
    float* out = (float*)d_out;

    char* ws = (char*)d_ws;
    int* ef = (int*)ws;                          // @0      (2 KB)
    int* et = (int*)(ws + 4096);                 // @4K     (2 KB)
    ushort_t* w1img = (ushort_t*)(ws + 8192);    // @8K     (128 KB)
    ushort_t* w2img = (ushort_t*)(ws + 139264);  // @136K   (~50 KB)
    ushort_t* X = (ushort_t*)(ws + 190464);      // X1 then X2, 4 MB each

    prep_kernel<<<45, 256, 0, stream>>>(e_f, e_t, W1, W2, ef, et, w1img, w2img);
    x_kernel<<<256, 256, 0, stream>>>(hidden, w1img, b1, X);
    gemm_payoff_kernel<<<992, 512, 0, stream>>>(X, X + 8192 * 256, ef, et, w2img, b2, out);
}